// Round 17
// baseline (136.714 us; speedup 1.0000x reference)
//
#include <hip/hip_runtime.h>
#include <hip/hip_bf16.h>

typedef __bf16 bf16_t;
typedef __bf16 bf16x8 __attribute__((ext_vector_type(8)));
typedef __bf16 bf16x4 __attribute__((ext_vector_type(4)));
typedef float f32x4 __attribute__((ext_vector_type(4)));
typedef float f32x16 __attribute__((ext_vector_type(16)));

#define NB 2
#define SEQ 2048
#define DMODEL 1024
#define NHEAD 16
#define DHEAD 64

#define PSWAP(x, y) asm("v_permlane32_swap_b32 %0, %1" : "+v"(x), "+v"(y))
#define CVTPK(d, a, b) asm("v_cvt_pk_bf16_f32 %0, %1, %2" : "=v"(d) : "v"(a), "v"(b))
#define WAITVM(n) asm volatile("s_waitcnt vmcnt(" #n ")" ::: "memory")
#define WAITLGKM0 asm volatile("s_waitcnt lgkmcnt(0)" ::: "memory")

__device__ inline void gload_lds16(const void* g, void* lds) {
  __builtin_amdgcn_global_load_lds((const __attribute__((address_space(1))) void*)g,
                                   (__attribute__((address_space(3))) void*)lds,
                                   16, 0, 0);
}

// ---------------- fused fp32 -> bf16 convert (H + 4 weights, one launch) ----------------
__global__ __launch_bounds__(256) void cvt_all_kernel(
    const float* __restrict__ H,  const float* __restrict__ Wq, const float* __restrict__ Wk,
    const float* __restrict__ Wv, const float* __restrict__ Wo,
    bf16_t* __restrict__ Hb, bf16_t* __restrict__ Wqb, bf16_t* __restrict__ Wkb,
    bf16_t* __restrict__ Wvb, bf16_t* __restrict__ Wob)
{
  const int b = blockIdx.x;
  const float* src; bf16_t* dst; int idx;
  if (b < 4096) { src = H; dst = Hb; idx = b; }
  else {
    const int r = b - 4096; const int s = r >> 10; idx = r & 1023;
    src = (s == 0) ? Wq : (s == 1) ? Wk : (s == 2) ? Wv : Wo;
    dst = (s == 0) ? Wqb : (s == 1) ? Wkb : (s == 2) ? Wvb : Wob;
  }
  const int i = idx * 256 + threadIdx.x;
  float4 v = ((const float4*)src)[i];
  bf16x4 o;
  o[0] = (bf16_t)v.x; o[1] = (bf16_t)v.y; o[2] = (bf16_t)v.z; o[3] = (bf16_t)v.w;
  ((bf16x4*)dst)[i] = o;
}

// ---------------- bf16 TN GEMM, counted-vmcnt double-buffer (R16, unchanged) ------------
template<int MODE>
__global__ __launch_bounds__(256, 3) void gemm_bt_kernel(
    const bf16_t* __restrict__ A,
    const bf16_t* __restrict__ W0, const bf16_t* __restrict__ W1, const bf16_t* __restrict__ W2,
    const float* __restrict__ bias0, const float* __restrict__ bias1, const float* __restrict__ bias2,
    void* out0, void* out1, void* out2)
{
  __shared__ char gsm[49152];
  const int tid = threadIdx.x;
  const int lane = tid & 63;
  const int w = tid >> 6;
  const int mt = blockIdx.y, nt = blockIdx.x, z = blockIdx.z;
  const bf16_t* Wp = (z == 0) ? W0 : ((z == 1) ? W1 : W2);
  const float* bp  = (z == 0) ? bias0 : ((z == 1) ? bias1 : bias2);

  const int wr = w & 1, wc = w >> 1;
  const int fr = lane & 15, fq = lane >> 4;

  const int r_in = lane >> 3;
  const int cswz = ((lane & 7) ^ (r_in & 7)) << 4;

  f32x4 acc[2][4] = {};

  const char* Ab = (const char*)(A + (size_t)mt * 64 * DMODEL);
  const char* Bb = (const char*)(Wp + (size_t)nt * 128 * DMODEL);

  const unsigned aA0 = (unsigned)__builtin_amdgcn_readfirstlane(w * 2048);
  const unsigned bB0 = (unsigned)__builtin_amdgcn_readfirstlane(16384 + w * 4096);

  #define GSTAGE(t, buf)                                                                   \
    do {                                                                                   \
      const size_t k0b_ = (size_t)(t) * 128;                                               \
      _Pragma("unroll")                                                                    \
      for (int i = 0; i < 2; ++i) {                                                        \
        const size_t rowA_ = (size_t)(w * 16 + i * 8 + r_in);                              \
        gload_lds16(Ab + rowA_ * (DMODEL * 2) + k0b_ + cswz,                               \
                    gsm + aA0 + (buf) * 8192 + i * 1024);                                  \
      }                                                                                    \
      _Pragma("unroll")                                                                    \
      for (int i = 0; i < 4; ++i) {                                                        \
        const size_t rowB_ = (size_t)(w * 32 + i * 8 + r_in);                              \
        gload_lds16(Bb + rowB_ * (DMODEL * 2) + k0b_ + cswz,                               \
                    gsm + bB0 + (buf) * 16384 + i * 1024);                                 \
      }                                                                                    \
    } while (0)

  #define GCOMPUTE(buf)                                                                    \
    do {                                                                                   \
      const char* As_ = gsm + (buf) * 8192;                                                \
      const char* Bs_ = gsm + 16384 + (buf) * 16384;                                       \
      bf16x8 a_[2][2], b_[4][2];                                                           \
      _Pragma("unroll")                                                                    \
      for (int m = 0; m < 2; ++m)                                                          \
        _Pragma("unroll")                                                                  \
        for (int ks = 0; ks < 2; ++ks)                                                     \
          a_[m][ks] = *(const bf16x8*)(As_ + (wr * 32 + m * 16 + fr) * 128 +               \
                                       ((ks * 64 + fq * 16) ^ ((fr & 7) << 4)));           \
      _Pragma("unroll")                                                                    \
      for (int n = 0; n < 4; ++n)                                                          \
        _Pragma("unroll")                                                                  \
        for (int ks = 0; ks < 2; ++ks)                                                     \
          b_[n][ks] = *(const bf16x8*)(Bs_ + (wc * 64 + n * 16 + fr) * 128 +               \
                                       ((ks * 64 + fq * 16) ^ ((fr & 7) << 4)));           \
      __builtin_amdgcn_s_setprio(1);                                                       \
      _Pragma("unroll")                                                                    \
      for (int m = 0; m < 2; ++m)                                                          \
        _Pragma("unroll")                                                                  \
        for (int n = 0; n < 4; ++n)                                                        \
          _Pragma("unroll")                                                                \
          for (int ks = 0; ks < 2; ++ks)                                                   \
            acc[m][n] = __builtin_amdgcn_mfma_f32_16x16x32_bf16(a_[m][ks], b_[n][ks],      \
                                                                acc[m][n], 0, 0, 0);       \
      __builtin_amdgcn_s_setprio(0);                                                       \
    } while (0)

  GSTAGE(0, 0);
  GSTAGE(1, 1);
  for (int t2 = 0; t2 < 7; ++t2) {
    WAITVM(6);
    __builtin_amdgcn_s_barrier();
    GCOMPUTE(0);
    __builtin_amdgcn_s_barrier();
    GSTAGE(2 * t2 + 2, 0);
    WAITVM(6);
    __builtin_amdgcn_s_barrier();
    GCOMPUTE(1);
    __builtin_amdgcn_s_barrier();
    GSTAGE(2 * t2 + 3, 1);
  }
  WAITVM(6);
  __builtin_amdgcn_s_barrier();
  GCOMPUTE(0);
  WAITVM(0);
  __builtin_amdgcn_s_barrier();
  GCOMPUTE(1);
  #undef GCOMPUTE
  #undef GSTAGE

  float bv[4];
  const int cb = nt * 128 + wc * 64;
  #pragma unroll
  for (int n = 0; n < 4; ++n) bv[n] = bp[cb + n * 16 + fr];

  if constexpr (MODE == 0) {
    float* outp = (float*)out0;
    #pragma unroll
    for (int m = 0; m < 2; ++m) {
      #pragma unroll
      for (int j = 0; j < 4; ++j) {
        const int row = mt * 64 + wr * 32 + m * 16 + fq * 4 + j;
        float* orow = outp + (size_t)row * DMODEL + cb;
        #pragma unroll
        for (int n = 0; n < 4; ++n)
          orow[n * 16 + fr] = acc[m][n][j] + bv[n];
      }
    }
  } else {
    const int h = nt * 2 + wc;
    if (z < 2) {
      #pragma unroll
      for (int m = 0; m < 2; ++m) {
        #pragma unroll
        for (int j = 0; j < 4; ++j) {
          float v0 = acc[m][0][j] + bv[0];
          float v1 = acc[m][1][j] + bv[1];
          float v2 = acc[m][2][j] + bv[2];
          float v3 = acc[m][3][j] + bv[3];
          float ss = v0 * v0 + v1 * v1 + v2 * v2 + v3 * v3;
          ss += __shfl_xor(ss, 1);
          ss += __shfl_xor(ss, 2);
          ss += __shfl_xor(ss, 4);
          ss += __shfl_xor(ss, 8);
          const float inv = 1.0f / fmaxf(sqrtf(ss), 1e-10f);
          const int row = mt * 64 + wr * 32 + m * 16 + fq * 4 + j;
          const int bb = row >> 11, sr = row & (SEQ - 1);
          bf16_t* op = ((z == 0) ? (bf16_t*)out0 : (bf16_t*)out1)
                       + (((size_t)(bb * NHEAD + h)) * SEQ + sr) * DHEAD;
          op[0 * 16 + fr] = (bf16_t)(v0 * inv);
          op[1 * 16 + fr] = (bf16_t)(v1 * inv);
          op[2 * 16 + fr] = (bf16_t)(v2 * inv);
          op[3 * 16 + fr] = (bf16_t)(v3 * inv);
        }
      }
    } else {
      __syncthreads();
      bf16_t* vt = (bf16_t*)gsm;          // [64][128] = 16KB
      #pragma unroll
      for (int m = 0; m < 2; ++m) {
        #pragma unroll
        for (int j = 0; j < 4; ++j) {
          float v0 = acc[m][0][j] + bv[0];
          float v1 = acc[m][1][j] + bv[1];
          float v2 = acc[m][2][j] + bv[2];
          float v3 = acc[m][3][j] + bv[3];
          float ss = v0 * v0 + v1 * v1 + v2 * v2 + v3 * v3;
          ss += __shfl_xor(ss, 1);
          ss += __shfl_xor(ss, 2);
          ss += __shfl_xor(ss, 4);
          ss += __shfl_xor(ss, 8);
          const float inv = 1.0f / fmaxf(sqrtf(ss), 1e-10f);
          const int r64 = wr * 32 + m * 16 + fq * 4 + j;
          vt[r64 * 128 + wc * 64 + 0 * 16 + fr] = (bf16_t)(v0 * inv);
          vt[r64 * 128 + wc * 64 + 1 * 16 + fr] = (bf16_t)(v1 * inv);
          vt[r64 * 128 + wc * 64 + 2 * 16 + fr] = (bf16_t)(v2 * inv);
          vt[r64 * 128 + wc * 64 + 3 * 16 + fr] = (bf16_t)(v3 * inv);
        }
      }
      __syncthreads();
      const int bb16 = (mt >> 5) * 16;
      const int srbase = (mt & 31) * 64;
      #pragma unroll
      for (int p = 0; p < 4; ++p) {
        const int id = p * 256 + tid;
        const int c = id >> 3;
        const int sc = (id & 7) * 8;
        bf16x8 vv;
        #pragma unroll
        for (int i = 0; i < 8; ++i)
          vv[i] = vt[(sc + i) * 128 + c];
        const int hh = nt * 2 + (c >> 6);
        const int dh = c & 63;
        bf16_t* gp = (bf16_t*)out2 + (((size_t)(bb16 + hh)) * 64 + dh) * (size_t)SEQ + srbase + sc;
        *(bf16x8*)gp = vv;
      }
    }
  }
}

// ---------------- MFMA spherical flash attention: producer/consumer wave split --------
// Block = 512 thr = 8 waves. Waves 0-3 = PRODUCERS (q-group g=w): read K frags, QK MFMA,
// score VALU, write packed PV B-fragments (P) to LDS. Waves 4-7 = CONSUMERS (g=w-4):
// read P + V frags, PV MFMA. Consumer runs one tile behind producer. Block owns all 2048
// keys (NT=32, no key split, no partials). LDS 64KB: K 2x8KB @0, V 2x8KB @16K, P 2x16KB
// @32K ([buf][g][slot 0..3][lane*16B], lane-contiguous = conflict-free b128).
// l computed by producers, handed via LDS at the end.
__device__ inline f32x16 sp16(float x) {
  f32x16 v;
  #pragma unroll
  for (int i = 0; i < 16; ++i) v[i] = x;
  return v;
}

// score transform w = exp(asin(c)/8) (scale-invariant, pure FMA) on the whole f32x16
// accumulator, then pack to the PV B-fragment pair via cvt_pk + permlane32_swap.
__device__ inline void score_pack(const f32x16& accp, float& l_acc, bf16x8& pf0, bf16x8& pf1) {
  const f32x16 c2 = accp * accp;
  f32x16 a = __builtin_elementwise_fma(c2, sp16(0.00379774f), sp16(0.00558036f));
  a = __builtin_elementwise_fma(c2, a, sp16(0.00937500f));
  a = __builtin_elementwise_fma(c2, a, sp16(0.02083333f));
  a = __builtin_elementwise_fma(c2, a, sp16(0.12500000f));
  const f32x16 s = a * accp;                              // asin(c)/8
  f32x16 e = __builtin_elementwise_fma(s, sp16(0.16666667f), sp16(0.5f));
  e = __builtin_elementwise_fma(s, e, sp16(1.0f));
  e = __builtin_elementwise_fma(s, e, sp16(1.0f));        // exp(s), deg-3
  const float t0 = (e[0] + e[1]) + (e[2] + e[3]);
  const float t1 = (e[4] + e[5]) + (e[6] + e[7]);
  const float t2 = (e[8] + e[9]) + (e[10] + e[11]);
  const float t3 = (e[12] + e[13]) + (e[14] + e[15]);
  l_acc += (t0 + t1) + (t2 + t3);
  unsigned dwA0, dwA1, dwA2, dwA3, dwB0, dwB1, dwB2, dwB3;
  CVTPK(dwA0, e[0], e[1]);   CVTPK(dwB0, e[2], e[3]);
  CVTPK(dwA1, e[4], e[5]);   CVTPK(dwB1, e[6], e[7]);
  CVTPK(dwA2, e[8], e[9]);   CVTPK(dwB2, e[10], e[11]);
  CVTPK(dwA3, e[12], e[13]); CVTPK(dwB3, e[14], e[15]);
  PSWAP(dwA0, dwA1);  PSWAP(dwB0, dwB1);
  PSWAP(dwA2, dwA3);  PSWAP(dwB2, dwB3);
  typedef unsigned u32x4_ __attribute__((ext_vector_type(4)));
  u32x4_ t0_ = { dwA0, dwB0, dwA1, dwB1 };
  u32x4_ t1_ = { dwA2, dwB2, dwA3, dwB3 };
  pf0 = __builtin_bit_cast(bf16x8, t0_);
  pf1 = __builtin_bit_cast(bf16x8, t1_);
}

__global__ __launch_bounds__(512, 2) void mfma_attn_kernel(
    const bf16_t* __restrict__ Qb, const bf16_t* __restrict__ Kb,
    const bf16_t* __restrict__ Vt, bf16_t* __restrict__ Oat)
{
  __shared__ char smem[65536];   // K[2][8K] @0 | V[2][8K] @16K | P[2][16K] @32K

  const int tid = threadIdx.x;
  const int lane = tid & 63;
  const int w = tid >> 6;
  const bool prod = (w < 4);
  const int g = w & 3;                  // q-group 0..3
  const int l31 = lane & 31, l5 = lane >> 5;
  const int NT = 32;                    // 64-key tiles (all 2048 keys)

  // grid 512; XCD-aware: xcd gets heads 4*xcd..4*xcd+3
  const int p = blockIdx.x;
  const int xcd = p & 7;
  const int j = p >> 3;                 // 0..63
  const int bh = xcd * 4 + (j >> 4);
  const int qt = j & 15;
  const int q0 = qt * 128 + g * 32;

  // producers hold Q B-fragments: lane holds Q[q=q0+l31][seg*16 + l5*8 .. +7]
  bf16x8 b_q[4];
  if (prod) {
    const bf16_t* Qp = Qb + ((size_t)bh * SEQ + q0 + l31) * DHEAD + l5 * 8;
    #pragma unroll
    for (int m = 0; m < 4; ++m)
      b_q[m] = *(const bf16x8*)(Qp + m * 16);
  }

  const char* Kbase = (const char*)(Kb + (size_t)bh * SEQ * DHEAD);
  const char* Vbase = (const char*)(Vt + (size_t)bh * DHEAD * SEQ);

  // staging geometry: each K (resp. V) 64-key tile = 8 chunks of 1KB; the 4 waves of a
  // role each own chunks 2g, 2g+1. Pre-swizzled per-lane global source offsets:
  const int chA = 2 * g, chB = 2 * g + 1;
  int koffA, koffB, voffA, voffB;
  {
    const int rA = chA * 4 + (lane >> 4), rB = chB * 4 + (lane >> 4);
    const int c = (lane & 15) * 16;
    const int cpA = c ^ ((rA & 15) << 4), cpB = c ^ ((rB & 15) << 4);
    koffA = (rA + ((cpA >> 7) << 5)) * 128 + (cpA & 127);
    koffB = (rB + ((cpB >> 7) << 5)) * 128 + (cpB & 127);
    voffA = (rA + ((cpA >> 7) << 5)) * (SEQ * 2) + (cpA & 127);
    voffB = (rB + ((cpB >> 7) << 5)) * (SEQ * 2) + (cpB & 127);
  }
  const unsigned chAo = (unsigned)__builtin_amdgcn_readfirstlane(chA * 1024);
  const unsigned chBo = (unsigned)__builtin_amdgcn_readfirstlane(chB * 1024);
  const unsigned pgo  = (unsigned)__builtin_amdgcn_readfirstlane(32768 + g * 4096);

  const int swz = (l31 & 15) << 4;
  const unsigned kRow = l31 * 256;

  f32x16 acc_o0 = {}, acc_o1 = {};
  float l_acc = 0.0f;

  #define STAGE_K(t, buf)                                                                  \
    do {                                                                                   \
      const char* Kt_ = Kbase + (size_t)(t) * 8192;                                        \
      gload_lds16(Kt_ + koffA, smem + (buf) * 8192 + chAo);                                \
      gload_lds16(Kt_ + koffB, smem + (buf) * 8192 + chBo);                                \
    } while (0)

  #define STAGE_V(t, buf)                                                                  \
    do {                                                                                   \
      const char* Vc_ = Vbase + (size_t)(t) * 128;                                         \
      gload_lds16(Vc_ + voffA, smem + 16384 + (buf) * 8192 + chAo);                        \
      gload_lds16(Vc_ + voffB, smem + 16384 + (buf) * 8192 + chBo);                        \
    } while (0)

  // producer tile: QK (both 32-key chunks, interleaved accp chains) -> score -> P write
  #define PROD_TILE(buf)                                                                   \
    do {                                                                                   \
      const char* kb_ = smem + (buf) * 8192 + kRow;                                        \
      f32x16 accp0 = {}, accp1 = {};                                                       \
      _Pragma("unroll")                                                                    \
      for (int m = 0; m < 4; ++m) {                                                        \
        bf16x8 akA = *(const bf16x8*)(kb_ + ((m * 32 + l5 * 16) ^ swz));                   \
        bf16x8 akB = *(const bf16x8*)(kb_ + ((128 + m * 32 + l5 * 16) ^ swz));             \
        accp0 = __builtin_amdgcn_mfma_f32_32x32x16_bf16(akA, b_q[m], accp0, 0, 0, 0);      \
        accp1 = __builtin_amdgcn_mfma_f32_32x32x16_bf16(akB, b_q[m], accp1, 0, 0, 0);      \
      }                                                                                    \
      char* Pw = smem + pgo + (buf) * 16384 + lane * 16;                                   \
      {                                                                                    \
        bf16x8 pf0, pf1;                                                                   \
        score_pack(accp0, l_acc, pf0, pf1);                                                \
        *(bf16x8*)(Pw + 0)    = pf0;                                                       \
        *(bf16x8*)(Pw + 1024) = pf1;                                                       \
      }                                                                                    \
      {                                                                                    \
        bf16x8 pf0, pf1;                                                                   \
        score_pack(accp1, l_acc, pf0, pf1);                                                \
        *(bf16x8*)(Pw + 2048) = pf0;                                                       \
        *(bf16x8*)(Pw + 3072) = pf1;                                                       \
      }                                                                                    \
      WAITLGKM0;                                                                           \
    } while (0)

  // consumer tile: read P + V frags, 8 PV MFMA (O^T[dh][q] accumulate)
  #define CONS_TILE(buf)                                                                   \
    do {                                                                                   \
      const char* Pr = smem + pgo + (buf) * 16384 + lane * 16;                             \
      bf16x8 pf00 = *(const bf16x8*)(Pr + 0);                                              \
      bf16x8 pf01 = *(const bf16x8*)(Pr + 1024);                                           \
      bf16x8 pf10 = *(const bf16x8*)(Pr + 2048);                                           \
      bf16x8 pf11 = *(const bf16x8*)(Pr + 3072);                                           \
      const char* vb_ = smem + 16384 + (buf) * 8192 + kRow;                                \
      bf16x8 av00 = *(const bf16x8*)(vb_ + ((  0 + l5 * 16) ^ swz));                       \
      bf16x8 av01 = *(const bf16x8*)(vb_ + (( 32 + l5 * 16) ^ swz));                       \
      bf16x8 av10 = *(const bf16x8*)(vb_ + ((128 +  0 + l5 * 16) ^ swz));                  \
      bf16x8 av11 = *(const bf16x8*)(vb_ + ((128 + 32 + l5 * 16) ^ swz));                  \
      bf16x8 bv00 = *(const bf16x8*)(vb_ + (( 64 +  0 + l5 * 16) ^ swz));                  \
      bf16x8 bv01 = *(const bf16x8*)(vb_ + (( 64 + 32 + l5 * 16) ^ swz));                  \
      bf16x8 bv10 = *(const bf16x8*)(vb_ + ((128 + 64 +  0 + l5 * 16) ^ swz));             \
      bf16x8 bv11 = *(const bf16x8*)(vb_ + ((128 + 64 + 32 + l5 * 16) ^ swz));             \
      __builtin_amdgcn_s_setprio(1);                                                       \
      acc_o0 = __builtin_amdgcn_mfma_f32_32x32x16_bf16(av00, pf00, acc_o0, 0, 0, 0);       \
      acc_o1 = __builtin_amdgcn_mfma_f32_32x32x16_bf16(av10, pf00, acc_o1, 0, 0, 0);       \
      acc_o0 = __builtin_amdgcn_mfma_f32_32x32x16_bf16(av01, pf01, acc_o0, 0, 0, 0);       \
      acc_o1 = __builtin_amdgcn_mfma_f32_32x32x16_bf16(av11, pf01, acc_o1, 0, 0, 0);       \
      acc_o0 = __builtin_amdgcn_mfma_f32_32x32x16_bf16(bv00, pf10, acc_o0, 0, 0, 0);       \
      acc_o1 = __builtin_amdgcn_mfma_f32_32x32x16_bf16(bv10, pf10, acc_o1, 0, 0, 0);       \
      acc_o0 = __builtin_amdgcn_mfma_f32_32x32x16_bf16(bv01, pf11, acc_o0, 0, 0, 0);       \
      acc_o1 = __builtin_amdgcn_mfma_f32_32x32x16_bf16(bv11, pf11, acc_o1, 0, 0, 0);       \
      __builtin_amdgcn_s_setprio(0);                                                       \
    } while (0)

  // prologue: prods stage K0->b0, K1->b1; cons stage V0->b0
  if (prod) { STAGE_K(0, 0); STAGE_K(1, 1); }
  else      { STAGE_V(0, 0); }

  for (int t = 0; t < NT; ++t) {
    if (t < NT - 2) { WAITVM(2); } else { WAITVM(0); }
    __builtin_amdgcn_s_barrier();
    // phase t: producer computes tile t; consumer computes tile t-1
    if (prod) PROD_TILE(t & 1);
    else if (t > 0) CONS_TILE((t - 1) & 1);
    __builtin_amdgcn_s_barrier();
    // post-barrier staging (all reads of the target buffers are complete)
    if (prod) { if (t < NT - 2) STAGE_K(t + 2, t & 1); }
    else      { if (t < NT - 1) STAGE_V(t + 1, (t + 1) & 1); }
  }
  // postlude: consumer finishes tile NT-1; producers publish l
  if (prod) {
    l_acc += __shfl_xor(l_acc, 32);
    if (lane < 32) ((float*)(smem + 32768))[g * 32 + l31] = l_acc;   // P buf0 region, free
    WAITLGKM0;
  } else {
    CONS_TILE((NT - 1) & 1);
  }
  __builtin_amdgcn_s_barrier();

  if (!prod) {
    const float lq = ((const float*)(smem + 32768))[g * 32 + l31];
    const float invl = __builtin_amdgcn_rcpf(lq);
    const int bb = bh >> 4, h = bh & 15;
    bf16_t* op = Oat + ((size_t)bb * SEQ + q0 + l31) * DMODEL + h * DHEAD;
    #pragma unroll
    for (int blk = 0; blk < 2; ++blk) {
      const f32x16& ao = blk ? acc_o1 : acc_o0;
      #pragma unroll
      for (int gg = 0; gg < 4; ++gg) {
        bf16x4 ov;
        ov[0] = (bf16_t)(ao[4 * gg + 0] * invl);
        ov[1] = (bf16_t)(ao[4 * gg + 1] * invl);
        ov[2] = (bf16_t)(ao[4 * gg + 2] * invl);
        ov[3] = (bf16_t)(ao[4 * gg + 3] * invl);
        *(bf16x4*)(op + blk * 32 + 8 * gg + 4 * l5) = ov;
      }
    }
  }
  #undef CONS_TILE
  #undef PROD_TILE
  #undef STAGE_V
  #undef STAGE_K
}

extern "C" void kernel_launch(void* const* d_in, const int* in_sizes, int n_in,
                              void* d_out, int out_size, void* d_ws, size_t ws_size,
                              hipStream_t stream)
{
  const float* H  = (const float*)d_in[0];
  const float* Wq = (const float*)d_in[1];
  const float* bq = (const float*)d_in[2];
  const float* Wk = (const float*)d_in[3];
  const float* bk = (const float*)d_in[4];
  const float* Wv = (const float*)d_in[5];
  const float* bv = (const float*)d_in[6];
  const float* Wo = (const float*)d_in[7];
  const float* bo = (const float*)d_in[8];
  float* out = (float*)d_out;

  char* ws = (char*)d_ws;
  bf16_t* Hb  = (bf16_t*)(ws);                    // 8 MB  [B*S][1024]
  bf16_t* Wqb = (bf16_t*)(ws + (8u << 20));       // 2 MB each
  bf16_t* Wkb = (bf16_t*)(ws + (10u << 20));
  bf16_t* Wvb = (bf16_t*)(ws + (12u << 20));
  bf16_t* Wob = (bf16_t*)(ws + (14u << 20));
  bf16_t* Qbf = (bf16_t*)(ws + (16u << 20));      // 8 MB  [BH][S][64]
  bf16_t* Kbf = (bf16_t*)(ws + (24u << 20));      // 8 MB  [BH][S][64]
  bf16_t* Vtb = (bf16_t*)(ws + (32u << 20));      // 8 MB  [BH][64][S]
  bf16_t* Oat = (bf16_t*)(ws + (40u << 20));      // 8 MB  [B][S][1024]

  // fp32 -> bf16 converts (single launch)
  cvt_all_kernel<<<8192, 256, 0, stream>>>(H, Wq, Wk, Wv, Wo, Hb, Wqb, Wkb, Wvb, Wob);

  // Q/K/V projections + bias + per-head normalize -> bf16 Q,K,[V^T]
  gemm_bt_kernel<1><<<dim3(8, 64, 3), 256, 0, stream>>>(
      Hb, Wqb, Wkb, Wvb, bq, bk, bv, Qbf, Kbf, Vtb);

  // MFMA spherical flash attention (producer/consumer wave split)
  mfma_attn_kernel<<<512, 512, 0, stream>>>(Qbf, Kbf, Vtb, Oat);

  // output projection -> d_out fp32 [B][S][1024]
  gemm_bt_kernel<0><<<dim3(8, 64, 1), 256, 0, stream>>>(
      Oat, Wob, Wob, Wob, bo, bo, bo, out, out, out);
}

// Round 18
// 122.509 us; speedup vs baseline: 1.1160x; 1.1160x over previous
//
#include <hip/hip_runtime.h>
#include <hip/hip_bf16.h>

typedef __bf16 bf16_t;
typedef __bf16 bf16x8 __attribute__((ext_vector_type(8)));
typedef __bf16 bf16x4 __attribute__((ext_vector_type(4)));
typedef float f32x4 __attribute__((ext_vector_type(4)));
typedef float f32x16 __attribute__((ext_vector_type(16)));

#define NB 2
#define SEQ 2048
#define DMODEL 1024
#define NHEAD 16
#define DHEAD 64

#define PSWAP(x, y) asm("v_permlane32_swap_b32 %0, %1" : "+v"(x), "+v"(y))
#define CVTPK(d, a, b) asm("v_cvt_pk_bf16_f32 %0, %1, %2" : "=v"(d) : "v"(a), "v"(b))
#define WAITVM(n) asm volatile("s_waitcnt vmcnt(" #n ")" ::: "memory")

__device__ inline void gload_lds16(const void* g, void* lds) {
  __builtin_amdgcn_global_load_lds((const __attribute__((address_space(1))) void*)g,
                                   (__attribute__((address_space(3))) void*)lds,
                                   16, 0, 0);
}

// ---------------- fused fp32 -> bf16 convert (H + 4 weights, one launch) ----------------
// 4096 blocks x 256 thr x 2 float4 = 8M floats (H 4M + weights 4x1M).
__global__ __launch_bounds__(256) void cvt_all_kernel(
    const float* __restrict__ H,  const float* __restrict__ Wq, const float* __restrict__ Wk,
    const float* __restrict__ Wv, const float* __restrict__ Wo,
    bf16_t* __restrict__ Hb, bf16_t* __restrict__ Wqb, bf16_t* __restrict__ Wkb,
    bf16_t* __restrict__ Wvb, bf16_t* __restrict__ Wob)
{
  #pragma unroll
  for (int r = 0; r < 2; ++r) {
    const int b = blockIdx.x * 2 + r;         // virtual block 0..8191
    const float* src; bf16_t* dst; int idx;
    if (b < 4096) { src = H; dst = Hb; idx = b; }
    else {
      const int q = b - 4096; const int s = q >> 10; idx = q & 1023;
      src = (s == 0) ? Wq : (s == 1) ? Wk : (s == 2) ? Wv : Wo;
      dst = (s == 0) ? Wqb : (s == 1) ? Wkb : (s == 2) ? Wvb : Wob;
    }
    const int i = idx * 256 + threadIdx.x;
    float4 v = ((const float4*)src)[i];
    bf16x4 o;
    o[0] = (bf16_t)v.x; o[1] = (bf16_t)v.y; o[2] = (bf16_t)v.z; o[3] = (bf16_t)v.w;
    ((bf16x4*)dst)[i] = o;
  }
}

// ---------------- bf16 TN GEMM, counted-vmcnt double-buffer (R16, unchanged) ------------
template<int MODE>
__global__ __launch_bounds__(256, 3) void gemm_bt_kernel(
    const bf16_t* __restrict__ A,
    const bf16_t* __restrict__ W0, const bf16_t* __restrict__ W1, const bf16_t* __restrict__ W2,
    const float* __restrict__ bias0, const float* __restrict__ bias1, const float* __restrict__ bias2,
    void* out0, void* out1, void* out2)
{
  __shared__ char gsm[49152];
  const int tid = threadIdx.x;
  const int lane = tid & 63;
  const int w = tid >> 6;
  const int mt = blockIdx.y, nt = blockIdx.x, z = blockIdx.z;
  const bf16_t* Wp = (z == 0) ? W0 : ((z == 1) ? W1 : W2);
  const float* bp  = (z == 0) ? bias0 : ((z == 1) ? bias1 : bias2);

  const int wr = w & 1, wc = w >> 1;
  const int fr = lane & 15, fq = lane >> 4;

  const int r_in = lane >> 3;
  const int cswz = ((lane & 7) ^ (r_in & 7)) << 4;

  f32x4 acc[2][4] = {};

  const char* Ab = (const char*)(A + (size_t)mt * 64 * DMODEL);
  const char* Bb = (const char*)(Wp + (size_t)nt * 128 * DMODEL);

  const unsigned aA0 = (unsigned)__builtin_amdgcn_readfirstlane(w * 2048);
  const unsigned bB0 = (unsigned)__builtin_amdgcn_readfirstlane(16384 + w * 4096);

  #define GSTAGE(t, buf)                                                                   \
    do {                                                                                   \
      const size_t k0b_ = (size_t)(t) * 128;                                               \
      _Pragma("unroll")                                                                    \
      for (int i = 0; i < 2; ++i) {                                                        \
        const size_t rowA_ = (size_t)(w * 16 + i * 8 + r_in);                              \
        gload_lds16(Ab + rowA_ * (DMODEL * 2) + k0b_ + cswz,                               \
                    gsm + aA0 + (buf) * 8192 + i * 1024);                                  \
      }                                                                                    \
      _Pragma("unroll")                                                                    \
      for (int i = 0; i < 4; ++i) {                                                        \
        const size_t rowB_ = (size_t)(w * 32 + i * 8 + r_in);                              \
        gload_lds16(Bb + rowB_ * (DMODEL * 2) + k0b_ + cswz,                               \
                    gsm + bB0 + (buf) * 16384 + i * 1024);                                 \
      }                                                                                    \
    } while (0)

  #define GCOMPUTE(buf)                                                                    \
    do {                                                                                   \
      const char* As_ = gsm + (buf) * 8192;                                                \
      const char* Bs_ = gsm + 16384 + (buf) * 16384;                                       \
      bf16x8 a_[2][2], b_[4][2];                                                           \
      _Pragma("unroll")                                                                    \
      for (int m = 0; m < 2; ++m)                                                          \
        _Pragma("unroll")                                                                  \
        for (int ks = 0; ks < 2; ++ks)                                                     \
          a_[m][ks] = *(const bf16x8*)(As_ + (wr * 32 + m * 16 + fr) * 128 +               \
                                       ((ks * 64 + fq * 16) ^ ((fr & 7) << 4)));           \
      _Pragma("unroll")                                                                    \
      for (int n = 0; n < 4; ++n)                                                          \
        _Pragma("unroll")                                                                  \
        for (int ks = 0; ks < 2; ++ks)                                                     \
          b_[n][ks] = *(const bf16x8*)(Bs_ + (wc * 64 + n * 16 + fr) * 128 +               \
                                       ((ks * 64 + fq * 16) ^ ((fr & 7) << 4)));           \
      __builtin_amdgcn_s_setprio(1);                                                       \
      _Pragma("unroll")                                                                    \
      for (int m = 0; m < 2; ++m)                                                          \
        _Pragma("unroll")                                                                  \
        for (int n = 0; n < 4; ++n)                                                        \
          _Pragma("unroll")                                                                \
          for (int ks = 0; ks < 2; ++ks)                                                   \
            acc[m][n] = __builtin_amdgcn_mfma_f32_16x16x32_bf16(a_[m][ks], b_[n][ks],      \
                                                                acc[m][n], 0, 0, 0);       \
      __builtin_amdgcn_s_setprio(0);                                                       \
    } while (0)

  GSTAGE(0, 0);
  GSTAGE(1, 1);
  for (int t2 = 0; t2 < 7; ++t2) {
    WAITVM(6);
    __builtin_amdgcn_s_barrier();
    GCOMPUTE(0);
    __builtin_amdgcn_s_barrier();
    GSTAGE(2 * t2 + 2, 0);
    WAITVM(6);
    __builtin_amdgcn_s_barrier();
    GCOMPUTE(1);
    __builtin_amdgcn_s_barrier();
    GSTAGE(2 * t2 + 3, 1);
  }
  WAITVM(6);
  __builtin_amdgcn_s_barrier();
  GCOMPUTE(0);
  WAITVM(0);
  __builtin_amdgcn_s_barrier();
  GCOMPUTE(1);
  #undef GCOMPUTE
  #undef GSTAGE

  float bv[4];
  const int cb = nt * 128 + wc * 64;
  #pragma unroll
  for (int n = 0; n < 4; ++n) bv[n] = bp[cb + n * 16 + fr];

  if constexpr (MODE == 0) {
    float* outp = (float*)out0;
    #pragma unroll
    for (int m = 0; m < 2; ++m) {
      #pragma unroll
      for (int j = 0; j < 4; ++j) {
        const int row = mt * 64 + wr * 32 + m * 16 + fq * 4 + j;
        float* orow = outp + (size_t)row * DMODEL + cb;
        #pragma unroll
        for (int n = 0; n < 4; ++n)
          orow[n * 16 + fr] = acc[m][n][j] + bv[n];
      }
    }
  } else {
    const int h = nt * 2 + wc;
    if (z < 2) {
      #pragma unroll
      for (int m = 0; m < 2; ++m) {
        #pragma unroll
        for (int j = 0; j < 4; ++j) {
          float v0 = acc[m][0][j] + bv[0];
          float v1 = acc[m][1][j] + bv[1];
          float v2 = acc[m][2][j] + bv[2];
          float v3 = acc[m][3][j] + bv[3];
          float ss = v0 * v0 + v1 * v1 + v2 * v2 + v3 * v3;
          ss += __shfl_xor(ss, 1);
          ss += __shfl_xor(ss, 2);
          ss += __shfl_xor(ss, 4);
          ss += __shfl_xor(ss, 8);
          const float inv = 1.0f / fmaxf(sqrtf(ss), 1e-10f);
          const int row = mt * 64 + wr * 32 + m * 16 + fq * 4 + j;
          const int bb = row >> 11, sr = row & (SEQ - 1);
          bf16_t* op = ((z == 0) ? (bf16_t*)out0 : (bf16_t*)out1)
                       + (((size_t)(bb * NHEAD + h)) * SEQ + sr) * DHEAD;
          op[0 * 16 + fr] = (bf16_t)(v0 * inv);
          op[1 * 16 + fr] = (bf16_t)(v1 * inv);
          op[2 * 16 + fr] = (bf16_t)(v2 * inv);
          op[3 * 16 + fr] = (bf16_t)(v3 * inv);
        }
      }
    } else {
      __syncthreads();
      bf16_t* vt = (bf16_t*)gsm;          // [64][128] = 16KB
      #pragma unroll
      for (int m = 0; m < 2; ++m) {
        #pragma unroll
        for (int j = 0; j < 4; ++j) {
          float v0 = acc[m][0][j] + bv[0];
          float v1 = acc[m][1][j] + bv[1];
          float v2 = acc[m][2][j] + bv[2];
          float v3 = acc[m][3][j] + bv[3];
          float ss = v0 * v0 + v1 * v1 + v2 * v2 + v3 * v3;
          ss += __shfl_xor(ss, 1);
          ss += __shfl_xor(ss, 2);
          ss += __shfl_xor(ss, 4);
          ss += __shfl_xor(ss, 8);
          const float inv = 1.0f / fmaxf(sqrtf(ss), 1e-10f);
          const int r64 = wr * 32 + m * 16 + fq * 4 + j;
          vt[r64 * 128 + wc * 64 + 0 * 16 + fr] = (bf16_t)(v0 * inv);
          vt[r64 * 128 + wc * 64 + 1 * 16 + fr] = (bf16_t)(v1 * inv);
          vt[r64 * 128 + wc * 64 + 2 * 16 + fr] = (bf16_t)(v2 * inv);
          vt[r64 * 128 + wc * 64 + 3 * 16 + fr] = (bf16_t)(v3 * inv);
        }
      }
      __syncthreads();
      const int bb16 = (mt >> 5) * 16;
      const int srbase = (mt & 31) * 64;
      #pragma unroll
      for (int p = 0; p < 4; ++p) {
        const int id = p * 256 + tid;
        const int c = id >> 3;
        const int sc = (id & 7) * 8;
        bf16x8 vv;
        #pragma unroll
        for (int i = 0; i < 8; ++i)
          vv[i] = vt[(sc + i) * 128 + c];
        const int hh = nt * 2 + (c >> 6);
        const int dh = c & 63;
        bf16_t* gp = (bf16_t*)out2 + (((size_t)(bb16 + hh)) * 64 + dh) * (size_t)SEQ + srbase + sc;
        *(bf16x8*)gp = vv;
      }
    }
  }
}

// ---------------- MFMA spherical flash attention (R16 proven version) -----------------
// Block = 512 thr = 8 waves: qw = w&3 (4 x 32 q-rows = 128 q), kh = w>>2 (2 x 1024 keys).
// LDS 64KB: [kh][buf][ K 8KB | V 8KB ], 64-key tiles, [32 rows][256B], c ^= (row&15)<<4.
// Counted-vmcnt double-buffer pipeline. Swapped QK^T (S[key][q], q=lane&31), P via
// cvt_pk + permlane32_swap, PV transposed. Score math vectorized over f32x16.
__device__ inline f32x16 sp16(float x) {
  f32x16 v;
  #pragma unroll
  for (int i = 0; i < 16; ++i) v[i] = x;
  return v;
}

__device__ inline void score_pack(const f32x16& accp, float& l_acc, bf16x8& pf0, bf16x8& pf1) {
  const f32x16 c2 = accp * accp;
  f32x16 a = __builtin_elementwise_fma(c2, sp16(0.00379774f), sp16(0.00558036f));
  a = __builtin_elementwise_fma(c2, a, sp16(0.00937500f));
  a = __builtin_elementwise_fma(c2, a, sp16(0.02083333f));
  a = __builtin_elementwise_fma(c2, a, sp16(0.12500000f));
  const f32x16 s = a * accp;                              // asin(c)/8
  f32x16 e = __builtin_elementwise_fma(s, sp16(0.16666667f), sp16(0.5f));
  e = __builtin_elementwise_fma(s, e, sp16(1.0f));
  e = __builtin_elementwise_fma(s, e, sp16(1.0f));        // exp(s), deg-3
  const float t0 = (e[0] + e[1]) + (e[2] + e[3]);
  const float t1 = (e[4] + e[5]) + (e[6] + e[7]);
  const float t2 = (e[8] + e[9]) + (e[10] + e[11]);
  const float t3 = (e[12] + e[13]) + (e[14] + e[15]);
  l_acc += (t0 + t1) + (t2 + t3);
  unsigned dwA0, dwA1, dwA2, dwA3, dwB0, dwB1, dwB2, dwB3;
  CVTPK(dwA0, e[0], e[1]);   CVTPK(dwB0, e[2], e[3]);
  CVTPK(dwA1, e[4], e[5]);   CVTPK(dwB1, e[6], e[7]);
  CVTPK(dwA2, e[8], e[9]);   CVTPK(dwB2, e[10], e[11]);
  CVTPK(dwA3, e[12], e[13]); CVTPK(dwB3, e[14], e[15]);
  PSWAP(dwA0, dwA1);  PSWAP(dwB0, dwB1);
  PSWAP(dwA2, dwA3);  PSWAP(dwB2, dwB3);
  typedef unsigned u32x4_ __attribute__((ext_vector_type(4)));
  u32x4_ t0_ = { dwA0, dwB0, dwA1, dwB1 };
  u32x4_ t1_ = { dwA2, dwB2, dwA3, dwB3 };
  pf0 = __builtin_bit_cast(bf16x8, t0_);
  pf1 = __builtin_bit_cast(bf16x8, t1_);
}

__global__ __launch_bounds__(512, 2) void mfma_attn_kernel(
    const bf16_t* __restrict__ Qb, const bf16_t* __restrict__ Kb,
    const bf16_t* __restrict__ Vt, bf16_t* __restrict__ Oat)
{
  __shared__ char smem[65536];   // [kh][buf][ K 8KB | V 8KB ]

  const int tid = threadIdx.x;
  const int lane = tid & 63;
  const int w = tid >> 6;
  const int qw = w & 3, kh = w >> 2;
  const int l31 = lane & 31, l5 = lane >> 5;

  // grid 512; XCD-aware: xcd gets heads 4*xcd..4*xcd+3 (L2 set ~2MB/XCD)
  const int p = blockIdx.x;
  const int xcd = p & 7;
  const int j = p >> 3;                 // 0..63
  const int bh = xcd * 4 + (j >> 4);
  const int qt = j & 15;
  const int q0 = qt * 128 + qw * 32;
  const int NT = 16;                    // 64-key tiles per key-half

  const bf16_t* Qp = Qb + ((size_t)bh * SEQ + q0 + l31) * DHEAD + l5 * 8;
  bf16x8 b_q[4];
  #pragma unroll
  for (int m = 0; m < 4; ++m)
    b_q[m] = *(const bf16x8*)(Qp + m * 16);

  const char* KbaseH = (const char*)(Kb + (size_t)bh * SEQ * DHEAD) + (size_t)kh * 1024 * DHEAD * 2;
  const char* VbaseH = (const char*)(Vt + (size_t)bh * DHEAD * SEQ) + (size_t)kh * 1024 * 2;

  const int chA = 2 * qw, chB = 2 * qw + 1;
  int koffA, koffB, voffA, voffB;
  {
    const int rA = chA * 4 + (lane >> 4), rB = chB * 4 + (lane >> 4);
    const int c = (lane & 15) * 16;
    const int cpA = c ^ ((rA & 15) << 4), cpB = c ^ ((rB & 15) << 4);
    koffA = (rA + ((cpA >> 7) << 5)) * 128 + (cpA & 127);
    koffB = (rB + ((cpB >> 7) << 5)) * 128 + (cpB & 127);
    voffA = (rA + ((cpA >> 7) << 5)) * (SEQ * 2) + (cpA & 127);
    voffB = (rB + ((cpB >> 7) << 5)) * (SEQ * 2) + (cpB & 127);
  }
  const unsigned stKA = (unsigned)__builtin_amdgcn_readfirstlane(kh * 32768 + chA * 1024);
  const unsigned stKB = (unsigned)__builtin_amdgcn_readfirstlane(kh * 32768 + chB * 1024);
  const unsigned rb0  = (unsigned)__builtin_amdgcn_readfirstlane(kh * 32768);

  const int swz = (l31 & 15) << 4;
  const unsigned kRow = l31 * 256;

  f32x16 acc_o0 = {}, acc_o1 = {};
  float l_acc = 0.0f;

  #define STAGE(t, buf)                                                                    \
    do {                                                                                   \
      const char* Kt_ = KbaseH + (size_t)(t) * 8192;                                       \
      const char* Vc_ = VbaseH + (size_t)(t) * 128;                                        \
      gload_lds16(Kt_ + koffA, smem + stKA + (buf) * 16384);                               \
      gload_lds16(Kt_ + koffB, smem + stKB + (buf) * 16384);                               \
      gload_lds16(Vc_ + voffA, smem + stKA + (buf) * 16384 + 8192);                        \
      gload_lds16(Vc_ + voffB, smem + stKB + (buf) * 16384 + 8192);                        \
    } while (0)

  #define TILE(buf)                                                                        \
    do {                                                                                   \
      const char* kb_ = smem + rb0 + (buf) * 16384 + kRow;                                 \
      const char* vb_ = smem + rb0 + (buf) * 16384 + 8192 + kRow;                          \
      f32x16 accp0 = {}, accp1 = {};                                                       \
      _Pragma("unroll")                                                                    \
      for (int m = 0; m < 4; ++m) {                                                        \
        bf16x8 akA = *(const bf16x8*)(kb_ + ((m * 32 + l5 * 16) ^ swz));                   \
        bf16x8 akB = *(const bf16x8*)(kb_ + ((128 + m * 32 + l5 * 16) ^ swz));             \
        accp0 = __builtin_amdgcn_mfma_f32_32x32x16_bf16(akA, b_q[m], accp0, 0, 0, 0);      \
        accp1 = __builtin_amdgcn_mfma_f32_32x32x16_bf16(akB, b_q[m], accp1, 0, 0, 0);      \
      }                                                                                    \
      {                                                                                    \
        bf16x8 pf0, pf1;                                                                   \
        score_pack(accp0, l_acc, pf0, pf1);                                                \
        bf16x8 av00 = *(const bf16x8*)(vb_ + ((  0 + l5 * 16) ^ swz));                     \
        bf16x8 av01 = *(const bf16x8*)(vb_ + (( 32 + l5 * 16) ^ swz));                     \
        bf16x8 av10 = *(const bf16x8*)(vb_ + ((128 +  0 + l5 * 16) ^ swz));                \
        bf16x8 av11 = *(const bf16x8*)(vb_ + ((128 + 32 + l5 * 16) ^ swz));                \
        acc_o0 = __builtin_amdgcn_mfma_f32_32x32x16_bf16(av00, pf0, acc_o0, 0, 0, 0);      \
        acc_o1 = __builtin_amdgcn_mfma_f32_32x32x16_bf16(av10, pf0, acc_o1, 0, 0, 0);      \
        acc_o0 = __builtin_amdgcn_mfma_f32_32x32x16_bf16(av01, pf1, acc_o0, 0, 0, 0);      \
        acc_o1 = __builtin_amdgcn_mfma_f32_32x32x16_bf16(av11, pf1, acc_o1, 0, 0, 0);      \
      }                                                                                    \
      {                                                                                    \
        bf16x8 pf0, pf1;                                                                   \
        score_pack(accp1, l_acc, pf0, pf1);                                                \
        bf16x8 av00 = *(const bf16x8*)(vb_ + (( 64 +  0 + l5 * 16) ^ swz));                \
        bf16x8 av01 = *(const bf16x8*)(vb_ + (( 64 + 32 + l5 * 16) ^ swz));                \
        bf16x8 av10 = *(const bf16x8*)(vb_ + ((128 + 64 +  0 + l5 * 16) ^ swz));           \
        bf16x8 av11 = *(const bf16x8*)(vb_ + ((128 + 64 + 32 + l5 * 16) ^ swz));           \
        acc_o0 = __builtin_amdgcn_mfma_f32_32x32x16_bf16(av00, pf0, acc_o0, 0, 0, 0);      \
        acc_o1 = __builtin_amdgcn_mfma_f32_32x32x16_bf16(av10, pf0, acc_o1, 0, 0, 0);      \
        acc_o0 = __builtin_amdgcn_mfma_f32_32x32x16_bf16(av01, pf1, acc_o0, 0, 0, 0);      \
        acc_o1 = __builtin_amdgcn_mfma_f32_32x32x16_bf16(av11, pf1, acc_o1, 0, 0, 0);      \
      }                                                                                    \
    } while (0)

  STAGE(0, 0);
  STAGE(1, 1);

  for (int t2 = 0; t2 < NT / 2 - 1; ++t2) {
    WAITVM(4);
    __builtin_amdgcn_s_barrier();
    TILE(0);
    __builtin_amdgcn_s_barrier();
    STAGE(2 * t2 + 2, 0);
    WAITVM(4);
    __builtin_amdgcn_s_barrier();
    TILE(1);
    __builtin_amdgcn_s_barrier();
    STAGE(2 * t2 + 3, 1);
  }
  WAITVM(4);
  __builtin_amdgcn_s_barrier();
  TILE(0);
  WAITVM(0);
  __builtin_amdgcn_s_barrier();
  TILE(1);
  #undef TILE
  #undef STAGE

  // ---- epilogue: finish l within wave, combine key halves via LDS, write Oat ----
  l_acc += __shfl_xor(l_acc, 32);

  __syncthreads();
  float* cO = (float*)smem;             // [qw][32][64] fp32 = 32 KB
  float* cL = (float*)(smem + 32768);   // [qw][64]
  if (kh == 1) {
    #pragma unroll
    for (int r = 0; r < 16; ++r) {
      cO[(qw * 32 + r) * 64 + lane] = acc_o0[r];
      cO[(qw * 32 + 16 + r) * 64 + lane] = acc_o1[r];
    }
    cL[qw * 64 + lane] = l_acc;
  }
  __syncthreads();
  if (kh == 0) {
    #pragma unroll
    for (int r = 0; r < 16; ++r) {
      acc_o0[r] += cO[(qw * 32 + r) * 64 + lane];
      acc_o1[r] += cO[(qw * 32 + 16 + r) * 64 + lane];
    }
    l_acc += cL[qw * 64 + lane];
    const float invl = __builtin_amdgcn_rcpf(l_acc);
    const int bb = bh >> 4, h = bh & 15;
    bf16_t* op = Oat + ((size_t)bb * SEQ + q0 + l31) * DMODEL + h * DHEAD;
    #pragma unroll
    for (int blk = 0; blk < 2; ++blk) {
      const f32x16& ao = blk ? acc_o1 : acc_o0;
      #pragma unroll
      for (int g = 0; g < 4; ++g) {
        bf16x4 ov;
        ov[0] = (bf16_t)(ao[4 * g + 0] * invl);
        ov[1] = (bf16_t)(ao[4 * g + 1] * invl);
        ov[2] = (bf16_t)(ao[4 * g + 2] * invl);
        ov[3] = (bf16_t)(ao[4 * g + 3] * invl);
        *(bf16x4*)(op + blk * 32 + 8 * g + 4 * l5) = ov;
      }
    }
  }
}

extern "C" void kernel_launch(void* const* d_in, const int* in_sizes, int n_in,
                              void* d_out, int out_size, void* d_ws, size_t ws_size,
                              hipStream_t stream)
{
  const float* H  = (const float*)d_in[0];
  const float* Wq = (const float*)d_in[1];
  const float* bq = (const float*)d_in[2];
  const float* Wk = (const float*)d_in[3];
  const float* bk = (const float*)d_in[4];
  const float* Wv = (const float*)d_in[5];
  const float* bv = (const float*)d_in[6];
  const float* Wo = (const float*)d_in[7];
  const float* bo = (const float*)d_in[8];
  float* out = (float*)d_out;

  char* ws = (char*)d_ws;
  bf16_t* Hb  = (bf16_t*)(ws);                    // 8 MB  [B*S][1024]
  bf16_t* Wqb = (bf16_t*)(ws + (8u << 20));       // 2 MB each
  bf16_t* Wkb = (bf16_t*)(ws + (10u << 20));
  bf16_t* Wvb = (bf16_t*)(ws + (12u << 20));
  bf16_t* Wob = (bf16_t*)(ws + (14u << 20));
  bf16_t* Qbf = (bf16_t*)(ws + (16u << 20));      // 8 MB  [BH][S][64]
  bf16_t* Kbf = (bf16_t*)(ws + (24u << 20));      // 8 MB  [BH][S][64]
  bf16_t* Vtb = (bf16_t*)(ws + (32u << 20));      // 8 MB  [BH][64][S]
  bf16_t* Oat = (bf16_t*)(ws + (40u << 20));      // 8 MB  [B][S][1024]

  // fp32 -> bf16 converts (single launch)
  cvt_all_kernel<<<4096, 256, 0, stream>>>(H, Wq, Wk, Wv, Wo, Hb, Wqb, Wkb, Wvb, Wob);

  // Q/K/V projections + bias + per-head normalize -> bf16 Q,K,[V^T]
  gemm_bt_kernel<1><<<dim3(8, 64, 3), 256, 0, stream>>>(
      Hb, Wqb, Wkb, Wvb, bq, bk, bv, Qbf, Kbf, Vtb);

  // MFMA spherical flash attention (8-wave, in-block key-split, counted-vmcnt pipeline)
  mfma_attn_kernel<<<512, 512, 0, stream>>>(Qbf, Kbf, Vtb, Oat);

  // output projection -> d_out fp32 [B][S][1024]
  gemm_bt_kernel<0><<<dim3(8, 64, 1), 256, 0, stream>>>(
      Oat, Wob, Wob, Wob, bo, bo, bo, out, out, out);
}

// Round 19
// 122.168 us; speedup vs baseline: 1.1191x; 1.0028x over previous
//
#include <hip/hip_runtime.h>
#include <hip/hip_bf16.h>

typedef __bf16 bf16_t;
typedef __bf16 bf16x8 __attribute__((ext_vector_type(8)));
typedef __bf16 bf16x4 __attribute__((ext_vector_type(4)));
typedef float f32x4 __attribute__((ext_vector_type(4)));
typedef float f32x16 __attribute__((ext_vector_type(16)));

#define NB 2
#define SEQ 2048
#define DMODEL 1024
#define NHEAD 16
#define DHEAD 64

#define PSWAP(x, y) asm("v_permlane32_swap_b32 %0, %1" : "+v"(x), "+v"(y))
#define CVTPK(d, a, b) asm("v_cvt_pk_bf16_f32 %0, %1, %2" : "=v"(d) : "v"(a), "v"(b))
#define WAITVM(n) asm volatile("s_waitcnt vmcnt(" #n ")" ::: "memory")

__device__ inline void gload_lds16(const void* g, void* lds) {
  __builtin_amdgcn_global_load_lds((const __attribute__((address_space(1))) void*)g,
                                   (__attribute__((address_space(3))) void*)lds,
                                   16, 0, 0);
}

// ---------------- fused fp32 -> bf16 convert (H + 4 weights, one launch) ----------------
__global__ __launch_bounds__(256) void cvt_all_kernel(
    const float* __restrict__ H,  const float* __restrict__ Wq, const float* __restrict__ Wk,
    const float* __restrict__ Wv, const float* __restrict__ Wo,
    bf16_t* __restrict__ Hb, bf16_t* __restrict__ Wqb, bf16_t* __restrict__ Wkb,
    bf16_t* __restrict__ Wvb, bf16_t* __restrict__ Wob)
{
  #pragma unroll
  for (int r = 0; r < 2; ++r) {
    const int b = blockIdx.x * 2 + r;         // virtual block 0..8191
    const float* src; bf16_t* dst; int idx;
    if (b < 4096) { src = H; dst = Hb; idx = b; }
    else {
      const int q = b - 4096; const int s = q >> 10; idx = q & 1023;
      src = (s == 0) ? Wq : (s == 1) ? Wk : (s == 2) ? Wv : Wo;
      dst = (s == 0) ? Wqb : (s == 1) ? Wkb : (s == 2) ? Wvb : Wob;
    }
    const int i = idx * 256 + threadIdx.x;
    float4 v = ((const float4*)src)[i];
    bf16x4 o;
    o[0] = (bf16_t)v.x; o[1] = (bf16_t)v.y; o[2] = (bf16_t)v.z; o[3] = (bf16_t)v.w;
    ((bf16x4*)dst)[i] = o;
  }
}

// ---------------- bf16 TN GEMM, counted-vmcnt double-buffer (R16, unchanged) ------------
template<int MODE>
__global__ __launch_bounds__(256, 3) void gemm_bt_kernel(
    const bf16_t* __restrict__ A,
    const bf16_t* __restrict__ W0, const bf16_t* __restrict__ W1, const bf16_t* __restrict__ W2,
    const float* __restrict__ bias0, const float* __restrict__ bias1, const float* __restrict__ bias2,
    void* out0, void* out1, void* out2)
{
  __shared__ char gsm[49152];
  const int tid = threadIdx.x;
  const int lane = tid & 63;
  const int w = tid >> 6;
  const int mt = blockIdx.y, nt = blockIdx.x, z = blockIdx.z;
  const bf16_t* Wp = (z == 0) ? W0 : ((z == 1) ? W1 : W2);
  const float* bp  = (z == 0) ? bias0 : ((z == 1) ? bias1 : bias2);

  const int wr = w & 1, wc = w >> 1;
  const int fr = lane & 15, fq = lane >> 4;

  const int r_in = lane >> 3;
  const int cswz = ((lane & 7) ^ (r_in & 7)) << 4;

  f32x4 acc[2][4] = {};

  const char* Ab = (const char*)(A + (size_t)mt * 64 * DMODEL);
  const char* Bb = (const char*)(Wp + (size_t)nt * 128 * DMODEL);

  const unsigned aA0 = (unsigned)__builtin_amdgcn_readfirstlane(w * 2048);
  const unsigned bB0 = (unsigned)__builtin_amdgcn_readfirstlane(16384 + w * 4096);

  #define GSTAGE(t, buf)                                                                   \
    do {                                                                                   \
      const size_t k0b_ = (size_t)(t) * 128;                                               \
      _Pragma("unroll")                                                                    \
      for (int i = 0; i < 2; ++i) {                                                        \
        const size_t rowA_ = (size_t)(w * 16 + i * 8 + r_in);                              \
        gload_lds16(Ab + rowA_ * (DMODEL * 2) + k0b_ + cswz,                               \
                    gsm + aA0 + (buf) * 8192 + i * 1024);                                  \
      }                                                                                    \
      _Pragma("unroll")                                                                    \
      for (int i = 0; i < 4; ++i) {                                                        \
        const size_t rowB_ = (size_t)(w * 32 + i * 8 + r_in);                              \
        gload_lds16(Bb + rowB_ * (DMODEL * 2) + k0b_ + cswz,                               \
                    gsm + bB0 + (buf) * 16384 + i * 1024);                                 \
      }                                                                                    \
    } while (0)

  #define GCOMPUTE(buf)                                                                    \
    do {                                                                                   \
      const char* As_ = gsm + (buf) * 8192;                                                \
      const char* Bs_ = gsm + 16384 + (buf) * 16384;                                       \
      bf16x8 a_[2][2], b_[4][2];                                                           \
      _Pragma("unroll")                                                                    \
      for (int m = 0; m < 2; ++m)                                                          \
        _Pragma("unroll")                                                                  \
        for (int ks = 0; ks < 2; ++ks)                                                     \
          a_[m][ks] = *(const bf16x8*)(As_ + (wr * 32 + m * 16 + fr) * 128 +               \
                                       ((ks * 64 + fq * 16) ^ ((fr & 7) << 4)));           \
      _Pragma("unroll")                                                                    \
      for (int n = 0; n < 4; ++n)                                                          \
        _Pragma("unroll")                                                                  \
        for (int ks = 0; ks < 2; ++ks)                                                     \
          b_[n][ks] = *(const bf16x8*)(Bs_ + (wc * 64 + n * 16 + fr) * 128 +               \
                                       ((ks * 64 + fq * 16) ^ ((fr & 7) << 4)));           \
      __builtin_amdgcn_s_setprio(1);                                                       \
      _Pragma("unroll")                                                                    \
      for (int m = 0; m < 2; ++m)                                                          \
        _Pragma("unroll")                                                                  \
        for (int n = 0; n < 4; ++n)                                                        \
          _Pragma("unroll")                                                                \
          for (int ks = 0; ks < 2; ++ks)                                                   \
            acc[m][n] = __builtin_amdgcn_mfma_f32_16x16x32_bf16(a_[m][ks], b_[n][ks],      \
                                                                acc[m][n], 0, 0, 0);       \
      __builtin_amdgcn_s_setprio(0);                                                       \
    } while (0)

  GSTAGE(0, 0);
  GSTAGE(1, 1);
  for (int t2 = 0; t2 < 7; ++t2) {
    WAITVM(6);
    __builtin_amdgcn_s_barrier();
    GCOMPUTE(0);
    __builtin_amdgcn_s_barrier();
    GSTAGE(2 * t2 + 2, 0);
    WAITVM(6);
    __builtin_amdgcn_s_barrier();
    GCOMPUTE(1);
    __builtin_amdgcn_s_barrier();
    GSTAGE(2 * t2 + 3, 1);
  }
  WAITVM(6);
  __builtin_amdgcn_s_barrier();
  GCOMPUTE(0);
  WAITVM(0);
  __builtin_amdgcn_s_barrier();
  GCOMPUTE(1);
  #undef GCOMPUTE
  #undef GSTAGE

  float bv[4];
  const int cb = nt * 128 + wc * 64;
  #pragma unroll
  for (int n = 0; n < 4; ++n) bv[n] = bp[cb + n * 16 + fr];

  if constexpr (MODE == 0) {
    float* outp = (float*)out0;
    #pragma unroll
    for (int m = 0; m < 2; ++m) {
      #pragma unroll
      for (int j = 0; j < 4; ++j) {
        const int row = mt * 64 + wr * 32 + m * 16 + fq * 4 + j;
        float* orow = outp + (size_t)row * DMODEL + cb;
        #pragma unroll
        for (int n = 0; n < 4; ++n)
          orow[n * 16 + fr] = acc[m][n][j] + bv[n];
      }
    }
  } else {
    const int h = nt * 2 + wc;
    if (z < 2) {
      #pragma unroll
      for (int m = 0; m < 2; ++m) {
        #pragma unroll
        for (int j = 0; j < 4; ++j) {
          float v0 = acc[m][0][j] + bv[0];
          float v1 = acc[m][1][j] + bv[1];
          float v2 = acc[m][2][j] + bv[2];
          float v3 = acc[m][3][j] + bv[3];
          float ss = v0 * v0 + v1 * v1 + v2 * v2 + v3 * v3;
          ss += __shfl_xor(ss, 1);
          ss += __shfl_xor(ss, 2);
          ss += __shfl_xor(ss, 4);
          ss += __shfl_xor(ss, 8);
          const float inv = 1.0f / fmaxf(sqrtf(ss), 1e-10f);
          const int row = mt * 64 + wr * 32 + m * 16 + fq * 4 + j;
          const int bb = row >> 11, sr = row & (SEQ - 1);
          bf16_t* op = ((z == 0) ? (bf16_t*)out0 : (bf16_t*)out1)
                       + (((size_t)(bb * NHEAD + h)) * SEQ + sr) * DHEAD;
          op[0 * 16 + fr] = (bf16_t)(v0 * inv);
          op[1 * 16 + fr] = (bf16_t)(v1 * inv);
          op[2 * 16 + fr] = (bf16_t)(v2 * inv);
          op[3 * 16 + fr] = (bf16_t)(v3 * inv);
        }
      }
    } else {
      __syncthreads();
      bf16_t* vt = (bf16_t*)gsm;          // [64][128] = 16KB
      #pragma unroll
      for (int m = 0; m < 2; ++m) {
        #pragma unroll
        for (int j = 0; j < 4; ++j) {
          float v0 = acc[m][0][j] + bv[0];
          float v1 = acc[m][1][j] + bv[1];
          float v2 = acc[m][2][j] + bv[2];
          float v3 = acc[m][3][j] + bv[3];
          float ss = v0 * v0 + v1 * v1 + v2 * v2 + v3 * v3;
          ss += __shfl_xor(ss, 1);
          ss += __shfl_xor(ss, 2);
          ss += __shfl_xor(ss, 4);
          ss += __shfl_xor(ss, 8);
          const float inv = 1.0f / fmaxf(sqrtf(ss), 1e-10f);
          const int r64 = wr * 32 + m * 16 + fq * 4 + j;
          vt[r64 * 128 + wc * 64 + 0 * 16 + fr] = (bf16_t)(v0 * inv);
          vt[r64 * 128 + wc * 64 + 1 * 16 + fr] = (bf16_t)(v1 * inv);
          vt[r64 * 128 + wc * 64 + 2 * 16 + fr] = (bf16_t)(v2 * inv);
          vt[r64 * 128 + wc * 64 + 3 * 16 + fr] = (bf16_t)(v3 * inv);
        }
      }
      __syncthreads();
      const int bb16 = (mt >> 5) * 16;
      const int srbase = (mt & 31) * 64;
      #pragma unroll
      for (int p = 0; p < 4; ++p) {
        const int id = p * 256 + tid;
        const int c = id >> 3;
        const int sc = (id & 7) * 8;
        bf16x8 vv;
        #pragma unroll
        for (int i = 0; i < 8; ++i)
          vv[i] = vt[(sc + i) * 128 + c];
        const int hh = nt * 2 + (c >> 6);
        const int dh = c & 63;
        bf16_t* gp = (bf16_t*)out2 + (((size_t)(bb16 + hh)) * 64 + dh) * (size_t)SEQ + srbase + sc;
        *(bf16x8*)gp = vv;
      }
    }
  }
}

// ---------------- MFMA spherical flash attention (R16 + l on the MFMA pipe) -----------
// Block = 512 thr = 8 waves: qw = w&3 (4 x 32 q-rows = 128 q), kh = w>>2 (2 x 1024 keys).
// LDS 64KB: [kh][buf][ K 8KB | V 8KB ], 64-key tiles, [32 rows][256B], c ^= (row&15)<<4.
// Counted-vmcnt double-buffer pipeline. Swapped QK^T (S[key][q], q=lane&31), P via
// cvt_pk + permlane32_swap, PV transposed. l = ones-A MFMA over pf (denominator = sum of
// bf16 P, consistent with numerator; removes the VALU reduction tree + epilogue shuffle).
__device__ inline f32x16 sp16(float x) {
  f32x16 v;
  #pragma unroll
  for (int i = 0; i < 16; ++i) v[i] = x;
  return v;
}

__device__ inline void score_pack(const f32x16& accp, bf16x8& pf0, bf16x8& pf1) {
  const f32x16 c2 = accp * accp;
  f32x16 a = __builtin_elementwise_fma(c2, sp16(0.00379774f), sp16(0.00558036f));
  a = __builtin_elementwise_fma(c2, a, sp16(0.00937500f));
  a = __builtin_elementwise_fma(c2, a, sp16(0.02083333f));
  a = __builtin_elementwise_fma(c2, a, sp16(0.12500000f));
  const f32x16 s = a * accp;                              // asin(c)/8
  f32x16 e = __builtin_elementwise_fma(s, sp16(0.16666667f), sp16(0.5f));
  e = __builtin_elementwise_fma(s, e, sp16(1.0f));
  e = __builtin_elementwise_fma(s, e, sp16(1.0f));        // exp(s), deg-3
  unsigned dwA0, dwA1, dwA2, dwA3, dwB0, dwB1, dwB2, dwB3;
  CVTPK(dwA0, e[0], e[1]);   CVTPK(dwB0, e[2], e[3]);
  CVTPK(dwA1, e[4], e[5]);   CVTPK(dwB1, e[6], e[7]);
  CVTPK(dwA2, e[8], e[9]);   CVTPK(dwB2, e[10], e[11]);
  CVTPK(dwA3, e[12], e[13]); CVTPK(dwB3, e[14], e[15]);
  PSWAP(dwA0, dwA1);  PSWAP(dwB0, dwB1);
  PSWAP(dwA2, dwA3);  PSWAP(dwB2, dwB3);
  typedef unsigned u32x4_ __attribute__((ext_vector_type(4)));
  u32x4_ t0_ = { dwA0, dwB0, dwA1, dwB1 };
  u32x4_ t1_ = { dwA2, dwB2, dwA3, dwB3 };
  pf0 = __builtin_bit_cast(bf16x8, t0_);
  pf1 = __builtin_bit_cast(bf16x8, t1_);
}

__global__ __launch_bounds__(512, 2) void mfma_attn_kernel(
    const bf16_t* __restrict__ Qb, const bf16_t* __restrict__ Kb,
    const bf16_t* __restrict__ Vt, bf16_t* __restrict__ Oat)
{
  __shared__ char smem[65536];   // [kh][buf][ K 8KB | V 8KB ]

  const int tid = threadIdx.x;
  const int lane = tid & 63;
  const int w = tid >> 6;
  const int qw = w & 3, kh = w >> 2;
  const int l31 = lane & 31, l5 = lane >> 5;

  // grid 512; XCD-aware: xcd gets heads 4*xcd..4*xcd+3 (L2 set ~2MB/XCD)
  const int p = blockIdx.x;
  const int xcd = p & 7;
  const int j = p >> 3;                 // 0..63
  const int bh = xcd * 4 + (j >> 4);
  const int qt = j & 15;
  const int q0 = qt * 128 + qw * 32;
  const int NT = 16;                    // 64-key tiles per key-half

  const bf16_t* Qp = Qb + ((size_t)bh * SEQ + q0 + l31) * DHEAD + l5 * 8;
  bf16x8 b_q[4];
  #pragma unroll
  for (int m = 0; m < 4; ++m)
    b_q[m] = *(const bf16x8*)(Qp + m * 16);

  bf16x8 a_one;
  #pragma unroll
  for (int i = 0; i < 8; ++i) a_one[i] = (bf16_t)1.0f;

  const char* KbaseH = (const char*)(Kb + (size_t)bh * SEQ * DHEAD) + (size_t)kh * 1024 * DHEAD * 2;
  const char* VbaseH = (const char*)(Vt + (size_t)bh * DHEAD * SEQ) + (size_t)kh * 1024 * 2;

  const int chA = 2 * qw, chB = 2 * qw + 1;
  int koffA, koffB, voffA, voffB;
  {
    const int rA = chA * 4 + (lane >> 4), rB = chB * 4 + (lane >> 4);
    const int c = (lane & 15) * 16;
    const int cpA = c ^ ((rA & 15) << 4), cpB = c ^ ((rB & 15) << 4);
    koffA = (rA + ((cpA >> 7) << 5)) * 128 + (cpA & 127);
    koffB = (rB + ((cpB >> 7) << 5)) * 128 + (cpB & 127);
    voffA = (rA + ((cpA >> 7) << 5)) * (SEQ * 2) + (cpA & 127);
    voffB = (rB + ((cpB >> 7) << 5)) * (SEQ * 2) + (cpB & 127);
  }
  const unsigned stKA = (unsigned)__builtin_amdgcn_readfirstlane(kh * 32768 + chA * 1024);
  const unsigned stKB = (unsigned)__builtin_amdgcn_readfirstlane(kh * 32768 + chB * 1024);
  const unsigned rb0  = (unsigned)__builtin_amdgcn_readfirstlane(kh * 32768);

  const int swz = (l31 & 15) << 4;
  const unsigned kRow = l31 * 256;

  f32x16 acc_o0 = {}, acc_o1 = {}, acc_l = {};

  #define STAGE(t, buf)                                                                    \
    do {                                                                                   \
      const char* Kt_ = KbaseH + (size_t)(t) * 8192;                                       \
      const char* Vc_ = VbaseH + (size_t)(t) * 128;                                        \
      gload_lds16(Kt_ + koffA, smem + stKA + (buf) * 16384);                               \
      gload_lds16(Kt_ + koffB, smem + stKB + (buf) * 16384);                               \
      gload_lds16(Vc_ + voffA, smem + stKA + (buf) * 16384 + 8192);                        \
      gload_lds16(Vc_ + voffB, smem + stKB + (buf) * 16384 + 8192);                        \
    } while (0)

  #define TILE(buf)                                                                        \
    do {                                                                                   \
      const char* kb_ = smem + rb0 + (buf) * 16384 + kRow;                                 \
      const char* vb_ = smem + rb0 + (buf) * 16384 + 8192 + kRow;                          \
      f32x16 accp0 = {}, accp1 = {};                                                       \
      _Pragma("unroll")                                                                    \
      for (int m = 0; m < 4; ++m) {                                                        \
        bf16x8 akA = *(const bf16x8*)(kb_ + ((m * 32 + l5 * 16) ^ swz));                   \
        bf16x8 akB = *(const bf16x8*)(kb_ + ((128 + m * 32 + l5 * 16) ^ swz));             \
        accp0 = __builtin_amdgcn_mfma_f32_32x32x16_bf16(akA, b_q[m], accp0, 0, 0, 0);      \
        accp1 = __builtin_amdgcn_mfma_f32_32x32x16_bf16(akB, b_q[m], accp1, 0, 0, 0);      \
      }                                                                                    \
      {                                                                                    \
        bf16x8 pf0, pf1;                                                                   \
        score_pack(accp0, pf0, pf1);                                                       \
        bf16x8 av00 = *(const bf16x8*)(vb_ + ((  0 + l5 * 16) ^ swz));                     \
        bf16x8 av01 = *(const bf16x8*)(vb_ + (( 32 + l5 * 16) ^ swz));                     \
        bf16x8 av10 = *(const bf16x8*)(vb_ + ((128 +  0 + l5 * 16) ^ swz));                \
        bf16x8 av11 = *(const bf16x8*)(vb_ + ((128 + 32 + l5 * 16) ^ swz));                \
        acc_o0 = __builtin_amdgcn_mfma_f32_32x32x16_bf16(av00, pf0, acc_o0, 0, 0, 0);      \
        acc_o1 = __builtin_amdgcn_mfma_f32_32x32x16_bf16(av10, pf0, acc_o1, 0, 0, 0);      \
        acc_l  = __builtin_amdgcn_mfma_f32_32x32x16_bf16(a_one, pf0, acc_l, 0, 0, 0);      \
        acc_o0 = __builtin_amdgcn_mfma_f32_32x32x16_bf16(av01, pf1, acc_o0, 0, 0, 0);      \
        acc_o1 = __builtin_amdgcn_mfma_f32_32x32x16_bf16(av11, pf1, acc_o1, 0, 0, 0);      \
        acc_l  = __builtin_amdgcn_mfma_f32_32x32x16_bf16(a_one, pf1, acc_l, 0, 0, 0);      \
      }                                                                                    \
      {                                                                                    \
        bf16x8 pf0, pf1;                                                                   \
        score_pack(accp1, pf0, pf1);                                                       \
        bf16x8 av00 = *(const bf16x8*)(vb_ + (( 64 +  0 + l5 * 16) ^ swz));                \
        bf16x8 av01 = *(const bf16x8*)(vb_ + (( 64 + 32 + l5 * 16) ^ swz));                \
        bf16x8 av10 = *(const bf16x8*)(vb_ + ((128 + 64 +  0 + l5 * 16) ^ swz));           \
        bf16x8 av11 = *(const bf16x8*)(vb_ + ((128 + 64 + 32 + l5 * 16) ^ swz));           \
        acc_o0 = __builtin_amdgcn_mfma_f32_32x32x16_bf16(av00, pf0, acc_o0, 0, 0, 0);      \
        acc_o1 = __builtin_amdgcn_mfma_f32_32x32x16_bf16(av10, pf0, acc_o1, 0, 0, 0);      \
        acc_l  = __builtin_amdgcn_mfma_f32_32x32x16_bf16(a_one, pf0, acc_l, 0, 0, 0);      \
        acc_o0 = __builtin_amdgcn_mfma_f32_32x32x16_bf16(av01, pf1, acc_o0, 0, 0, 0);      \
        acc_o1 = __builtin_amdgcn_mfma_f32_32x32x16_bf16(av11, pf1, acc_o1, 0, 0, 0);      \
        acc_l  = __builtin_amdgcn_mfma_f32_32x32x16_bf16(a_one, pf1, acc_l, 0, 0, 0);      \
      }                                                                                    \
    } while (0)

  STAGE(0, 0);
  STAGE(1, 1);

  for (int t2 = 0; t2 < NT / 2 - 1; ++t2) {
    WAITVM(4);
    __builtin_amdgcn_s_barrier();
    TILE(0);
    __builtin_amdgcn_s_barrier();
    STAGE(2 * t2 + 2, 0);
    WAITVM(4);
    __builtin_amdgcn_s_barrier();
    TILE(1);
    __builtin_amdgcn_s_barrier();
    STAGE(2 * t2 + 3, 1);
  }
  WAITVM(4);
  __builtin_amdgcn_s_barrier();
  TILE(0);
  WAITVM(0);
  __builtin_amdgcn_s_barrier();
  TILE(1);
  #undef TILE
  #undef STAGE

  // ---- epilogue: l = acc_l[0] (all rows identical), combine key halves, write Oat ----
  const float l_half = acc_l[0];

  __syncthreads();
  float* cO = (float*)smem;             // [qw][32][64] fp32 = 32 KB
  float* cL = (float*)(smem + 32768);   // [qw][64]
  if (kh == 1) {
    #pragma unroll
    for (int r = 0; r < 16; ++r) {
      cO[(qw * 32 + r) * 64 + lane] = acc_o0[r];
      cO[(qw * 32 + 16 + r) * 64 + lane] = acc_o1[r];
    }
    cL[qw * 64 + lane] = l_half;
  }
  __syncthreads();
  if (kh == 0) {
    #pragma unroll
    for (int r = 0; r < 16; ++r) {
      acc_o0[r] += cO[(qw * 32 + r) * 64 + lane];
      acc_o1[r] += cO[(qw * 32 + 16 + r) * 64 + lane];
    }
    const float l_tot = l_half + cL[qw * 64 + lane];
    const float invl = __builtin_amdgcn_rcpf(l_tot);
    const int bb = bh >> 4, h = bh & 15;
    bf16_t* op = Oat + ((size_t)bb * SEQ + q0 + l31) * DMODEL + h * DHEAD;
    #pragma unroll
    for (int blk = 0; blk < 2; ++blk) {
      const f32x16& ao = blk ? acc_o1 : acc_o0;
      #pragma unroll
      for (int g = 0; g < 4; ++g) {
        bf16x4 ov;
        ov[0] = (bf16_t)(ao[4 * g + 0] * invl);
        ov[1] = (bf16_t)(ao[4 * g + 1] * invl);
        ov[2] = (bf16_t)(ao[4 * g + 2] * invl);
        ov[3] = (bf16_t)(ao[4 * g + 3] * invl);
        *(bf16x4*)(op + blk * 32 + 8 * g + 4 * l5) = ov;
      }
    }
  }
}

extern "C" void kernel_launch(void* const* d_in, const int* in_sizes, int n_in,
                              void* d_out, int out_size, void* d_ws, size_t ws_size,
                              hipStream_t stream)
{
  const float* H  = (const float*)d_in[0];
  const float* Wq = (const float*)d_in[1];
  const float* bq = (const float*)d_in[2];
  const float* Wk = (const float*)d_in[3];
  const float* bk = (const float*)d_in[4];
  const float* Wv = (const float*)d_in[5];
  const float* bv = (const float*)d_in[6];
  const float* Wo = (const float*)d_in[7];
  const float* bo = (const float*)d_in[8];
  float* out = (float*)d_out;

  char* ws = (char*)d_ws;
  bf16_t* Hb  = (bf16_t*)(ws);                    // 8 MB  [B*S][1024]
  bf16_t* Wqb = (bf16_t*)(ws + (8u << 20));       // 2 MB each
  bf16_t* Wkb = (bf16_t*)(ws + (10u << 20));
  bf16_t* Wvb = (bf16_t*)(ws + (12u << 20));
  bf16_t* Wob = (bf16_t*)(ws + (14u << 20));
  bf16_t* Qbf = (bf16_t*)(ws + (16u << 20));      // 8 MB  [BH][S][64]
  bf16_t* Kbf = (bf16_t*)(ws + (24u << 20));      // 8 MB  [BH][S][64]
  bf16_t* Vtb = (bf16_t*)(ws + (32u << 20));      // 8 MB  [BH][64][S]
  bf16_t* Oat = (bf16_t*)(ws + (40u << 20));      // 8 MB  [B][S][1024]

  // fp32 -> bf16 converts (single launch)
  cvt_all_kernel<<<4096, 256, 0, stream>>>(H, Wq, Wk, Wv, Wo, Hb, Wqb, Wkb, Wvb, Wob);

  // Q/K/V projections + bias + per-head normalize -> bf16 Q,K,[V^T]
  gemm_bt_kernel<1><<<dim3(8, 64, 3), 256, 0, stream>>>(
      Hb, Wqb, Wkb, Wvb, bq, bk, bv, Qbf, Kbf, Vtb);

  // MFMA spherical flash attention
  mfma_attn_kernel<<<512, 512, 0, stream>>>(Qbf, Kbf, Vtb, Oat);

  // output projection -> d_out fp32 [B][S][1024]
  gemm_bt_kernel<0><<<dim3(8, 64, 1), 256, 0, stream>>>(
      Oat, Wob, Wob, Wob, bo, bo, bo, out, out, out);
}